// Round 6
// baseline (299.434 us; speedup 1.0000x reference)
//
#include <hip/hip_runtime.h>
#include <hip/hip_bf16.h>

// Problem constants
#define Bc   2
#define Nc   4096
#define Hc   4
#define HIDc 256
#define VDc  64

typedef short s8v  __attribute__((ext_vector_type(8)));
typedef float f4v  __attribute__((ext_vector_type(4)));

static __device__ __forceinline__ unsigned short bf16bits(float f) {
    __hip_bfloat16 h = __float2bfloat16(f);
    return *(unsigned short*)&h;
}

// ---------------------------------------------------------------------------
// K1 (fused): blocks 0..127 = W-prep (bf16 hi/lo split into MFMA-A-fragment-
// linear layout); blocks 128..8319 = per-row exact 30th percentile + row min.
// Thresh: windowed histogram on [0.25,0.35] (ranks 1228/1229 of U[0,1) rows
// land there with ~7 sigma margin); exact full-range fallback if not.
// ---------------------------------------------------------------------------
__global__ __launch_bounds__(256) void front_kernel(
    const float* __restrict__ m_dist, const float* __restrict__ wgt,
    unsigned short* __restrict__ wh, unsigned short* __restrict__ wl,
    float* __restrict__ thr_out, float* __restrict__ min_out)
{
    int t = threadIdx.x, bid = blockIdx.x;

    if (bid < 128) {
        int h  = bid >> 5;
        int kt = (bid >> 3) & 3;
        int jc = bid & 7;
        int lane = t >> 2, ii = t & 3;
        #pragma unroll
        for (int u = 0; u < 2; u++) {
            int i = ii * 2 + u;
            int j = jc * 32 + (lane >> 4) * 8 + i;
            int k = kt * 16 + (lane & 15);
            float v = wgt[((size_t)h * HIDc + j) * VDc + k];
            __hip_bfloat16 hb = __float2bfloat16(v);
            float hf = __bfloat162float(hb);
            size_t o = ((((size_t)h * 4 + kt) * 8 + jc) * 64 + lane) * 8 + i;
            wh[o] = *(unsigned short*)&hb;
            wl[o] = bf16bits(v - hf);
        }
        return;
    }

    __shared__ unsigned int hist[1024];
    __shared__ float wredf[4];
    __shared__ unsigned int wsum[4];
    __shared__ unsigned int wscan[4];
    __shared__ int b0s, b1s;
    __shared__ unsigned int c0s;
    __shared__ unsigned int ncand;
    __shared__ float cand[256];
    __shared__ float s0s, s1s;

    size_t rowid = bid - 128;
    const float* row = m_dist + rowid * Nc;

    float4 vals[4];
    float lmin = 1e30f;
    #pragma unroll
    for (int i = 0; i < 4; i++) {
        float4 v = ((const float4*)row)[t + i * 256];
        vals[i] = v;
        lmin = fminf(lmin, fminf(fminf(v.x, v.y), fminf(v.z, v.w)));
    }
    #pragma unroll
    for (int o = 32; o > 0; o >>= 1) lmin = fminf(lmin, __shfl_xor(lmin, o));
    if ((t & 63) == 0) wredf[t >> 6] = lmin;

    const unsigned int R0 = 1228u, R1 = 1229u;
    float wlo = 0.25f, whi = 0.35f;
    int b0 = 0, b1 = 0;
    unsigned int C0 = 0;

    for (;;) {
        float wscale = 1024.0f / (whi - wlo);

        for (int i = t; i < 1024; i += 256) hist[i] = 0u;
        if (t == 0) ncand = 0u;
        __syncthreads();

        unsigned int cb = 0;
        #pragma unroll
        for (int i = 0; i < 4; i++) {
            float a[4] = {vals[i].x, vals[i].y, vals[i].z, vals[i].w};
            #pragma unroll
            for (int j = 0; j < 4; j++) {
                float v = a[j];
                if (v < wlo) {
                    cb++;
                } else {
                    int bx = (int)((v - wlo) * wscale);
                    if (bx < 1024) atomicAdd(&hist[bx], 1u);
                }
            }
        }
        #pragma unroll
        for (int o = 32; o > 0; o >>= 1) cb += __shfl_xor(cb, o);
        if ((t & 63) == 0) wsum[t >> 6] = cb;
        __syncthreads();
        unsigned int Cb = wsum[0] + wsum[1] + wsum[2] + wsum[3];

        unsigned int c[4], csum = 0;
        #pragma unroll
        for (int j = 0; j < 4; j++) { c[j] = hist[t * 4 + j]; csum += c[j]; }
        unsigned int inc = csum;
        #pragma unroll
        for (int o = 1; o < 64; o <<= 1) {
            unsigned int nv = __shfl_up(inc, o);
            if ((t & 63) >= o) inc += nv;
        }
        if ((t & 63) == 63) wscan[t >> 6] = inc;
        __syncthreads();
        unsigned int wpref = 0;
        for (int wv = 0; wv < (t >> 6); wv++) wpref += wscan[wv];
        unsigned int T = wscan[0] + wscan[1] + wscan[2] + wscan[3];
        unsigned int P = Cb + wpref + inc - csum;

        unsigned int cum = P;
        #pragma unroll
        for (int j = 0; j < 4; j++) {
            unsigned int lo = cum, hi = cum + c[j];
            if (R0 >= lo && R0 < hi) { b0s = t * 4 + j; c0s = lo; }
            if (R1 >= lo && R1 < hi) { b1s = t * 4 + j; }
            cum = hi;
        }
        __syncthreads();

        if (Cb <= R0 && R1 < Cb + T) { b0 = b0s; b1 = b1s; C0 = c0s; break; }
        wlo = 0.0f; whi = 1.001f;
    }

    float wscale = 1024.0f / (whi - wlo);
    #pragma unroll
    for (int i = 0; i < 4; i++) {
        float a[4] = {vals[i].x, vals[i].y, vals[i].z, vals[i].w};
        #pragma unroll
        for (int j = 0; j < 4; j++) {
            float v = a[j];
            if (v >= wlo) {
                int bx = (int)((v - wlo) * wscale);
                if (bx >= b0 && bx <= b1) {
                    unsigned int p = atomicAdd(&ncand, 1u);
                    if (p < 256u) cand[p] = v;
                }
            }
        }
    }
    __syncthreads();
    unsigned int nc = min(ncand, 256u);
    if ((unsigned int)t < nc) {
        float v = cand[t];
        unsigned int rk = C0;
        for (unsigned int j = 0; j < nc; j++) {
            float u = cand[j];
            rk += (u < v || (u == v && j < (unsigned int)t)) ? 1u : 0u;
        }
        if (rk == R0) s0s = v;
        if (rk == R1) s1s = v;
    }
    __syncthreads();
    if (t == 0) {
        thr_out[rowid] = 0.5f * (s0s + s1s);
        min_out[rowid] = fminf(fminf(wredf[0], wredf[1]), fminf(wredf[2], wredf[3]));
    }
}

// ---------------------------------------------------------------------------
// K2: V^T via MFMA, 3-term bf16 split (Ah*Bh + Al*Bh + Ah*Bl ~ f32-accurate).
// x converted f32 -> bf16 hi/lo inline. VT[b,h,k,n] bf16 directly.
// grid = B*H*(N/64) = 512 blocks x 256 (4 waves; wave w owns n-subtile w).
// ---------------------------------------------------------------------------
__global__ __launch_bounds__(256) void value_kernel(
    const float* __restrict__ x,
    const unsigned short* __restrict__ wh, const unsigned short* __restrict__ wl,
    unsigned short* __restrict__ vt_g)
{
    int t  = threadIdx.x;
    int bid = blockIdx.x;
    int nt = bid & 63;
    int h  = (bid >> 6) & 3;
    int b  = bid >> 8;
    int n0 = nt * 64;

    int w = t >> 6, lane = t & 63, q4 = lane >> 4, m16 = lane & 15;
    int nb = n0 + w * 16;

    const float* xp = x + ((size_t)(b * Nc + nb + m16)) * HIDc + q4 * 8;

    f4v acc[4];
    #pragma unroll
    for (int kt = 0; kt < 4; kt++) acc[kt] = (f4v){0.f, 0.f, 0.f, 0.f};

    #pragma unroll
    for (int jc = 0; jc < 8; jc++) {
        float4 xv0 = *(const float4*)(xp + jc * 32);
        float4 xv1 = *(const float4*)(xp + jc * 32 + 4);
        float f[8] = {xv0.x, xv0.y, xv0.z, xv0.w, xv1.x, xv1.y, xv1.z, xv1.w};
        union { s8v v; unsigned short u[8]; } hs, ls;
        #pragma unroll
        for (int i = 0; i < 8; i++) {
            __hip_bfloat16 hb = __float2bfloat16(f[i]);
            float hf = __bfloat162float(hb);
            hs.u[i] = *(unsigned short*)&hb;
            ls.u[i] = bf16bits(f[i] - hf);
        }
        #pragma unroll
        for (int kt = 0; kt < 4; kt++) {
            size_t ao = (((size_t)(h * 4 + kt) * 8 + jc) << 9) + lane * 8;
            s8v ah = *(const s8v*)(wh + ao);
            s8v al = *(const s8v*)(wl + ao);
            acc[kt] = __builtin_amdgcn_mfma_f32_16x16x32_bf16(ah, hs.v, acc[kt], 0, 0, 0);
            acc[kt] = __builtin_amdgcn_mfma_f32_16x16x32_bf16(al, hs.v, acc[kt], 0, 0, 0);
            acc[kt] = __builtin_amdgcn_mfma_f32_16x16x32_bf16(ah, ls.v, acc[kt], 0, 0, 0);
        }
    }

    unsigned short* vg = vt_g + (((size_t)b * Hc + h) * VDc) * Nc;
    #pragma unroll
    for (int kt = 0; kt < 4; kt++) {
        #pragma unroll
        for (int rg = 0; rg < 4; rg++) {
            int k = kt * 16 + q4 * 4 + rg;
            vg[(size_t)k * Nc + nb + m16] = bf16bits(acc[kt][rg]);
        }
    }
}

// ---------------------------------------------------------------------------
// K3: fused mask + softmax-numerator + PV (bf16 MFMA), split-K over j.
// R6: LDS-VOLUME cut (R3-R5 latency fixes were flat -> attn is LDS/VALU
// throughput-bound, 120 KB LDS traffic per block-iter):
//  - ms LDS tile ELIMINATED: A-values loaded per-lane DIRECTLY from global
//    m_dist (2x float4; dense 16x128B rectangle/wave; the waves sharing rows
//    hit L1/L2). Removes 32KB LDS read + 8KB write + 512-thread DMA per iter.
//  - 8 waves = 4 heads x 2 row-halves; each wave owns 32 rows via two A-frags
//    sharing ONE set of B-frags: 4 ds_read_b128 feed 8 MFMAs (vt re-read
//    halves: 64KB -> 32KB per block-iter).
//  LDS/iter: 120KB -> 48KB for the same output. Sync skeleton = R5 (proven):
//  3-stage vt buffers, one raw s_barrier/iter, counted vmcnt. Reg-loads are
//  part of the vmcnt count (in-order retirement): steady wait = vmcnt(2)
//  [leaves only next STAGE's 2 DMAs in flight]. 2-step unroll keeps reg
//  buffers statically indexed (rule #20); LDS buffer rotates via pointers.
//  Numerics: per-lane w-values, MFMA j-order, reduction trees identical to
//  R5 -> bit-identical output (absmax change = race canary).
// ---------------------------------------------------------------------------
#define NT 64
#define JT 32

__global__ __launch_bounds__(512, 4) void attn_kernel(
    const float* __restrict__ m_dist, const float* __restrict__ rr,
    const unsigned short* __restrict__ vt_g,
    const float* __restrict__ thr_g, const float* __restrict__ min_g,
    float* __restrict__ Op, float* __restrict__ Zp, int jlen)
{
    __shared__ unsigned short vtL[3][Hc * VDc * JT];   // 3 x 16 KB

    int t = threadIdx.x;
    const int nblk = Bc * (Nc / NT);        // 128
    int js = blockIdx.x / nblk;
    int rb = blockIdx.x - js * nblk;
    int b  = rb >> 6;                       // Nc/NT = 64 row-tiles
    int n0 = (rb & 63) * NT;
    int j0 = js * jlen;

    int lane = t & 63, q = lane >> 4, m16 = lane & 15;
    int w = t >> 6;                         // wave 0..7
    int h = w & 3, rhalf = w >> 2;          // head, row-half
    int row0 = rhalf * 32 + m16;            // rows owned: row0 (g0), row0+16 (g1)
    int row1 = row0 + 16;

    float mn0 = min_g[b * Nc + n0 + row0];
    float mn1 = min_g[b * Nc + n0 + row1];
    float th0 = thr_g[b * Nc + n0 + row0];
    float th1 = thr_g[b * Nc + n0 + row1];
    float rv = rr[h];
    float cc = -(rv * rv) * 1.4426950408889634f;   // -r^2 * log2(e)
    float nm0 = -mn0 * cc, nm1 = -mn1 * cc;

    f4v acc0[4], acc1[4];
    #pragma unroll
    for (int ct = 0; ct < 4; ct++) {
        acc0[ct] = (f4v){0.f, 0.f, 0.f, 0.f};
        acc1[ct] = (f4v){0.f, 0.f, 0.f, 0.f};
    }
    float z0 = 0.f, z1 = 0.f;

    // direct A-source pointers (per-lane): m[row][j0 + q*8 ...]
    const float* mb0 = m_dist + ((size_t)(b * Nc + n0 + row0)) * Nc + j0 + q * 8;
    const float* mb1 = mb0 + (size_t)16 * Nc;

    // vt DMA staging (512 threads x 2): rows t>>2 and (t>>2)+128, phys chunk
    // t&3, logical source chunk (t&3)^(row&3); LDS dest linear = slot*16 B.
    const unsigned short* vtb = vt_g + ((size_t)b * Hc * VDc) * Nc + j0;
    int vrow = t >> 2;
    const unsigned short* vsrc  = vtb + (size_t)vrow * Nc + (((t & 3) ^ (vrow & 3)) << 3);
    const unsigned short* vsrc2 = vsrc + (size_t)128 * Nc;

    // B-read swizzled 16B-chunk (ushort offset within row); brow&3 == m16&3
    int bco = (q ^ (m16 & 3)) << 3;
    const int hoff = h * VDc * JT;

    int niter = jlen / JT;

    char* L0 = (char*)&vtL[0][0];
    char* L1 = (char*)&vtL[1][0];
    char* L2 = (char*)&vtL[2][0];

    #define STAGE(k, LB) do {                                                  \
        size_t jo_ = (size_t)(k) * JT;                                         \
        __builtin_amdgcn_global_load_lds(                                      \
            (const __attribute__((address_space(1))) void*)(vsrc + jo_),       \
            (__attribute__((address_space(3))) void*)((LB) + (size_t)t * 16),  \
            16, 0, 0);                                                         \
        __builtin_amdgcn_global_load_lds(                                      \
            (const __attribute__((address_space(1))) void*)(vsrc2 + jo_),      \
            (__attribute__((address_space(3))) void*)((LB) + 8192 + (size_t)t * 16), \
            16, 0, 0);                                                         \
    } while (0)

    #define RLOAD(k, r00, r01, r10, r11) do {                                  \
        size_t jo_ = (size_t)(k) * JT;                                         \
        r00 = *(const float4*)(mb0 + jo_);                                     \
        r01 = *(const float4*)(mb0 + jo_ + 4);                                 \
        r10 = *(const float4*)(mb1 + jo_);                                     \
        r11 = *(const float4*)(mb1 + jo_ + 4);                                 \
    } while (0)

    #define COMPUTE(r00, r01, r10, r11, LB) do {                               \
        const unsigned short* vb_ = (const unsigned short*)(LB) + hoff;        \
        float w0 = (r00.x <= th0) ? __builtin_amdgcn_exp2f(__builtin_fmaf(r00.x, cc, nm0)) : 0.f; \
        float w1 = (r00.y <= th0) ? __builtin_amdgcn_exp2f(__builtin_fmaf(r00.y, cc, nm0)) : 0.f; \
        float w2 = (r00.z <= th0) ? __builtin_amdgcn_exp2f(__builtin_fmaf(r00.z, cc, nm0)) : 0.f; \
        float w3 = (r00.w <= th0) ? __builtin_amdgcn_exp2f(__builtin_fmaf(r00.w, cc, nm0)) : 0.f; \
        float w4 = (r01.x <= th0) ? __builtin_amdgcn_exp2f(__builtin_fmaf(r01.x, cc, nm0)) : 0.f; \
        float w5 = (r01.y <= th0) ? __builtin_amdgcn_exp2f(__builtin_fmaf(r01.y, cc, nm0)) : 0.f; \
        float w6 = (r01.z <= th0) ? __builtin_amdgcn_exp2f(__builtin_fmaf(r01.z, cc, nm0)) : 0.f; \
        float w7 = (r01.w <= th0) ? __builtin_amdgcn_exp2f(__builtin_fmaf(r01.w, cc, nm0)) : 0.f; \
        z0 += ((w0 + w1) + (w2 + w3)) + ((w4 + w5) + (w6 + w7));               \
        float v0 = (r10.x <= th1) ? __builtin_amdgcn_exp2f(__builtin_fmaf(r10.x, cc, nm1)) : 0.f; \
        float v1 = (r10.y <= th1) ? __builtin_amdgcn_exp2f(__builtin_fmaf(r10.y, cc, nm1)) : 0.f; \
        float v2 = (r10.z <= th1) ? __builtin_amdgcn_exp2f(__builtin_fmaf(r10.z, cc, nm1)) : 0.f; \
        float v3 = (r10.w <= th1) ? __builtin_amdgcn_exp2f(__builtin_fmaf(r10.w, cc, nm1)) : 0.f; \
        float v4 = (r11.x <= th1) ? __builtin_amdgcn_exp2f(__builtin_fmaf(r11.x, cc, nm1)) : 0.f; \
        float v5 = (r11.y <= th1) ? __builtin_amdgcn_exp2f(__builtin_fmaf(r11.y, cc, nm1)) : 0.f; \
        float v6 = (r11.z <= th1) ? __builtin_amdgcn_exp2f(__builtin_fmaf(r11.z, cc, nm1)) : 0.f; \
        float v7 = (r11.w <= th1) ? __builtin_amdgcn_exp2f(__builtin_fmaf(r11.w, cc, nm1)) : 0.f; \
        z1 += ((v0 + v1) + (v2 + v3)) + ((v4 + v5) + (v6 + v7));               \
        union { s8v v; __hip_bfloat162 h2[4]; } af0, af1;                      \
        af0.h2[0] = __float22bfloat162_rn((float2){w0, w1});                   \
        af0.h2[1] = __float22bfloat162_rn((float2){w2, w3});                   \
        af0.h2[2] = __float22bfloat162_rn((float2){w4, w5});                   \
        af0.h2[3] = __float22bfloat162_rn((float2){w6, w7});                   \
        af1.h2[0] = __float22bfloat162_rn((float2){v0, v1});                   \
        af1.h2[1] = __float22bfloat162_rn((float2){v2, v3});                   \
        af1.h2[2] = __float22bfloat162_rn((float2){v4, v5});                   \
        af1.h2[3] = __float22bfloat162_rn((float2){v6, v7});                   \
        _Pragma("unroll")                                                      \
        for (int ct_ = 0; ct_ < 4; ct_++) {                                    \
            int brow_ = ct_ * 16 + m16;                                        \
            s8v bf_ = *(const s8v*)(vb_ + brow_ * JT + bco);                   \
            acc0[ct_] = __builtin_amdgcn_mfma_f32_16x16x32_bf16(af0.v, bf_, acc0[ct_], 0, 0, 0); \
            acc1[ct_] = __builtin_amdgcn_mfma_f32_16x16x32_bf16(af1.v, bf_, acc1[ct_], 0, 0, 0); \
        }                                                                      \
    } while (0)

    float4 rA00, rA01, rA10, rA11;
    float4 rB00, rB01, rB10, rB11;

    // prologue: issue order S(0), R(0), S(1)  (order pinned for vmcnt count)
    STAGE(0, L0);
    __builtin_amdgcn_sched_barrier(0);
    RLOAD(0, rA00, rA01, rA10, rA11);
    __builtin_amdgcn_sched_barrier(0);
    STAGE(1, L1);
    __builtin_amdgcn_sched_barrier(0);

    for (int it = 0; it < niter; it += 2) {
        // ---- even sub-iter (uses rA, L0) ----
        // in flight: S(it)2, R(it)4, S(it+1)2  -> retire S(it)+R(it)
        asm volatile("s_waitcnt vmcnt(2)" ::: "memory");
        __builtin_amdgcn_sched_barrier(0);
        __builtin_amdgcn_s_barrier();
        __builtin_amdgcn_sched_barrier(0);
        RLOAD(it + 1, rB00, rB01, rB10, rB11);
        __builtin_amdgcn_sched_barrier(0);
        if (it + 2 < niter) STAGE(it + 2, L2);
        __builtin_amdgcn_sched_barrier(0);
        COMPUTE(rA00, rA01, rA10, rA11, L0);

        // ---- odd sub-iter (uses rB, L1) ----
        if (it + 2 < niter) { asm volatile("s_waitcnt vmcnt(2)" ::: "memory"); }
        else                { asm volatile("s_waitcnt vmcnt(0)" ::: "memory"); }
        __builtin_amdgcn_sched_barrier(0);
        __builtin_amdgcn_s_barrier();
        __builtin_amdgcn_sched_barrier(0);
        if (it + 2 < niter) {
            RLOAD(it + 2, rA00, rA01, rA10, rA11);
            __builtin_amdgcn_sched_barrier(0);
            if (it + 3 < niter) STAGE(it + 3, L0);
            __builtin_amdgcn_sched_barrier(0);
        }
        COMPUTE(rB00, rB01, rB10, rB11, L1);

        char* tmp = L0; L0 = L2; L2 = L1; L1 = tmp;
    }
    #undef STAGE
    #undef RLOAD
    #undef COMPUTE

    // Z: lanes sharing m16 across q (xor 16, 32)
    z0 += __shfl_xor(z0, 16); z0 += __shfl_xor(z0, 32);
    z1 += __shfl_xor(z1, 16); z1 += __shfl_xor(z1, 32);
    if (q == 0) {
        size_t zb = (((size_t)js * Bc + b) * Hc + h) * Nc + n0;
        Zp[zb + row0] = z0;
        Zp[zb + row1] = z1;
    }

    // partial O: D row = q*4+rg (within each 16), col = ct*16+m16
    #pragma unroll
    for (int ct = 0; ct < 4; ct++) {
        #pragma unroll
        for (int rg = 0; rg < 4; rg++) {
            int nl = rhalf * 32 + q * 4 + rg;
            size_t ob = (((size_t)js * Bc + b) * Nc + n0 + nl) * HIDc + h * VDc + ct * 16 + m16;
            Op[ob] = acc0[ct][rg];
            Op[ob + (size_t)16 * HIDc] = acc1[ct][rg];
        }
    }
}

// ---------------------------------------------------------------------------
// K4: combine split-K partials, normalize, exact GELU. f32x4 per thread.
// grid = B*N*HID/1024 = 2048 blocks x 256.  (unchanged)
// ---------------------------------------------------------------------------
__global__ __launch_bounds__(256) void combine_kernel(
    const float* __restrict__ Op, const float* __restrict__ Zp,
    float* __restrict__ out, int S)
{
    int g = blockIdx.x * 256 + threadIdx.x;       // float4 index
    int c4 = g & 63;
    int n  = (g >> 6) & (Nc - 1);
    int b  = g >> 18;                             // 64 * 4096 = 2^18
    int h  = c4 >> 4;

    float z = 0.f;
    float4 v = {0.f, 0.f, 0.f, 0.f};
    for (int s = 0; s < S; s++) {
        z += Zp[(((size_t)s * Bc + b) * Hc + h) * Nc + n];
        float4 p = *(const float4*)&Op[(((size_t)s * Bc + b) * Nc + n) * HIDc + c4 * 4];
        v.x += p.x; v.y += p.y; v.z += p.z; v.w += p.w;
    }
    float iz = 1.0f / z;
    float4 o;
    float u;
    u = v.x * iz; o.x = 0.5f * u * (1.0f + erff(u * 0.7071067811865476f));
    u = v.y * iz; o.y = 0.5f * u * (1.0f + erff(u * 0.7071067811865476f));
    u = v.z * iz; o.z = 0.5f * u * (1.0f + erff(u * 0.7071067811865476f));
    u = v.w * iz; o.w = 0.5f * u * (1.0f + erff(u * 0.7071067811865476f));
    *(float4*)&out[(((size_t)b * Nc + n) * HIDc) + c4 * 4] = o;
}

// ---------------------------------------------------------------------------
extern "C" void kernel_launch(void* const* d_in, const int* in_sizes, int n_in,
                              void* d_out, int out_size, void* d_ws, size_t ws_size,
                              hipStream_t stream) {
    const float* m_dist = (const float*)d_in[0];
    const float* x      = (const float*)d_in[1];
    const float* r      = (const float*)d_in[2];
    const float* weight = (const float*)d_in[3];
    float* out = (float*)d_out;

    char* ws = (char*)d_ws;
    const size_t MB = 1024 * 1024;
    unsigned short* vt = (unsigned short*)ws;            // 4 MiB bf16 VT
    float* thr = (float*)(ws + 4 * MB);                  // 32 KiB
    float* mn  = (float*)(ws + 4 * MB + 32 * 1024);      // 32 KiB
    float* Zp  = (float*)(ws + 4 * MB + 64 * 1024);      // up to 512 KiB
    float* Op  = (float*)(ws + 5 * MB);                  // S * 8 MiB

    const size_t OpSz = (size_t)Bc * Nc * HIDc * 4;      // 8 MiB
    // split factor: prefer 4, else 2, else 1 (needs 5MB + S*OpSz + 256KB)
    int S = 4;
    if (ws_size < 6 * MB + 4 * OpSz) S = 2;
    if (ws_size < 6 * MB + 2 * OpSz) S = 1;
    int jlen = Nc / S;

    // W hi/lo fragment buffers after Op (128 KiB each)
    char* pb = ws + 5 * MB + (size_t)S * OpSz;
    unsigned short* wh = (unsigned short*)pb;
    unsigned short* wl = (unsigned short*)(pb + 128 * 1024);

    front_kernel<<<128 + Bc * Nc, 256, 0, stream>>>(m_dist, weight, wh, wl, thr, mn);
    value_kernel<<<512, 256, 0, stream>>>(x, wh, wl, vt);
    attn_kernel<<<S * Bc * (Nc / NT), 512, 0, stream>>>(m_dist, r, vt, thr, mn, Op, Zp, jlen);
    combine_kernel<<<(Bc * Nc * HIDc) / 1024, 256, 0, stream>>>(Op, Zp, out, S);
}